// Round 9
// baseline (378.270 us; speedup 1.0000x reference)
//
#include <hip/hip_runtime.h>
#include <hip/hip_bf16.h>

typedef __bf16 bf16_t;
typedef __bf16 bf16x8 __attribute__((ext_vector_type(8)));
typedef float  floatx4 __attribute__((ext_vector_type(4)));

#define BQ 16
#define NTOK 2048

// ---------------- Kernel 0: W -> W^T bf16, + zero out-accumulator & rowsums ----------------
__global__ __launch_bounds__(256) void k_prep(const float* __restrict__ Wq,
                                              const float* __restrict__ Wk,
                                              const float* __restrict__ Wv,
                                              bf16_t* __restrict__ wt,
                                              float* __restrict__ outz,
                                              float* __restrict__ rsz) {
    int o = blockIdx.x * 256 + threadIdx.x;   // grid 1024 -> o < 262144
    if (o < 49152) {
        int w = o >> 14;
        int r = o & 16383;
        int h = r >> 8;
        int d = r & 255;
        const float* W = (w == 0) ? Wq : ((w == 1) ? Wk : Wv);
        wt[o] = (bf16_t)W[d * 64 + h];
    }
    float4 z = make_float4(0.f, 0.f, 0.f, 0.f);
    for (int u = o; u < 532480; u += 262144) {
        if (u < 524288) ((float4*)outz)[u] = z;
        else            ((float4*)rsz)[u - 524288] = z;
    }
}

// ---------------- Kernel 1: QKV projection (32 tokens/block, 1024 blocks) ----------------
#define XS 264
#define VS 40
__global__ __launch_bounds__(256) void k_qkv(const float* __restrict__ x,
                                             const bf16_t* __restrict__ wt,
                                             const float* __restrict__ bq,
                                             const float* __restrict__ bk,
                                             const float* __restrict__ bv,
                                             bf16_t* __restrict__ qb,
                                             bf16_t* __restrict__ kb,
                                             bf16_t* __restrict__ vt) {
    __shared__ bf16_t x_ls[32 * XS];
    __shared__ bf16_t vt_ls[64 * VS];

    int b  = blockIdx.x >> 6;
    int t0 = (blockIdx.x & 63) << 5;
    int t  = threadIdx.x;
    int lane = t & 63;
    int w    = t >> 6;
    int m_   = lane & 15;
    int q4   = lane >> 4;

    for (int tau = t; tau < 2048; tau += 256) {
        int row = tau >> 6, ch = tau & 63;
        float4 v = ((const float4*)x)[(size_t)(b * NTOK + t0 + row) * 64 + ch];
        bf16_t tmp[4] = {(bf16_t)v.x, (bf16_t)v.y, (bf16_t)v.z, (bf16_t)v.w};
        *(uint2*)(&x_ls[row * XS + ch * 4]) = *(uint2*)tmp;
    }
    __syncthreads();

    for (int wi = 0; wi < 3; ++wi) {
        const bf16_t* wtw = wt + wi * 16384;
        floatx4 acc[2];
        #pragma unroll
        for (int mt = 0; mt < 2; ++mt) acc[mt] = floatx4{0.f, 0.f, 0.f, 0.f};

        #pragma unroll
        for (int ks = 0; ks < 8; ++ks) {
            bf16x8 bfrag = *(const bf16x8*)(wtw + (16 * w + m_) * 256 + ks * 32 + q4 * 8);
            #pragma unroll
            for (int mt = 0; mt < 2; ++mt) {
                bf16x8 afrag = *(const bf16x8*)(&x_ls[(16 * mt + m_) * XS + ks * 32 + q4 * 8]);
                acc[mt] = __builtin_amdgcn_mfma_f32_16x16x32_bf16(afrag, bfrag, acc[mt], 0, 0, 0);
            }
        }
        const float* bias_p = (wi == 0) ? bq : ((wi == 1) ? bk : bv);
        float bias = bias_p[16 * w + m_];
        float scale = (wi == 0) ? 0.125f : 1.0f;   // fold H^-0.5 into q (exact pow2)

        if (wi < 2) {
            bf16_t* dst = (wi == 0) ? qb : kb;
            #pragma unroll
            for (int mt = 0; mt < 2; ++mt)
                #pragma unroll
                for (int r = 0; r < 4; ++r) {
                    int tok = t0 + 16 * mt + 4 * q4 + r;
                    dst[(size_t)(b * NTOK + tok) * 64 + 16 * w + m_] = (bf16_t)((acc[mt][r] + bias) * scale);
                }
        } else {
            #pragma unroll
            for (int mt = 0; mt < 2; ++mt)
                #pragma unroll
                for (int r = 0; r < 4; ++r)
                    vt_ls[(16 * w + m_) * VS + 16 * mt + 4 * q4 + r] = (bf16_t)(acc[mt][r] + bias);
            __syncthreads();
            {
                int h = t >> 2, ch = t & 3;
                uint4 val = *(const uint4*)(&vt_ls[h * VS + ch * 8]);
                *(uint4*)(vt + (size_t)(b * 64 + h) * NTOK + t0 + ch * 8) = val;
            }
        }
    }
}

// ---------------- Kernel 2: fused attention — BARRIER-FREE K-loop ----------------
// Block = 4 independent waves. Rows: frame 48 (46bx-1 .. 46bx+46, interior 1..46).
// Cols per iter: wave w computes A for 16 cols starting aw0 = 56*it - 1 + 14*w
// (1-col overlap with neighbors), produces conv/P only for its middle 14 (m_ in 1..14).
// PV: per-wave partial O over all 64 h, K=32 MFMA with P cols 16..31 == 0.
// 37 col-iters, 3 chunks of <=13.
#define PST 40    // pls stride (bf16): 80 B rows, 16B-aligned
#define NIT 37
#define GX 45
__global__ __launch_bounds__(256) void k_attn(const bf16_t* __restrict__ qb,
                                              const bf16_t* __restrict__ kb,
                                              const bf16_t* __restrict__ vt,
                                              const float* __restrict__ conv_w,
                                              const float* __restrict__ conv_b,
                                              float* __restrict__ outp,
                                              float* __restrict__ rsg) {
    __shared__ __align__(16) char smem[15360];  // pls: 4 waves x 48 x PST bf16; scr overlay 48x64 f32

    int b  = blockIdx.z;
    int bx = blockIdx.x;
    int it0   = blockIdx.y * 13;
    int itEnd = (it0 + 13 < NIT) ? (it0 + 13) : NIT;
    int t = threadIdx.x, lane = t & 63, w = t >> 6;
    int m_ = lane & 15, q4 = lane >> 4;

    bf16_t* pls = (bf16_t*)smem + w * (48 * PST);   // wave-private
    float*  scr = (float*)smem;                      // epilogue overlay

    float cw[9];
    #pragma unroll
    for (int i = 0; i < 9; ++i) cw[i] = conv_w[i];
    float cb = conv_b[0];

    // zero own pls region (wave-local; cols 16..31 stay zero forever = P K-pad)
    for (int u = lane; u < 48 * PST / 2; u += 64) ((uint*)pls)[u] = 0u;

    // ---- one-time: q fragments (A-operand) ----
    bf16x8 qf[3][2];
    {
        int tokq = 46 * bx - 1 + m_;
        #pragma unroll
        for (int si = 0; si < 3; ++si) {
            int tok = tokq + 16 * si;
            bool ok = (tok >= 0) && (tok < NTOK);
            #pragma unroll
            for (int ks = 0; ks < 2; ++ks) {
                bf16x8 v = {};
                if (ok) v = *(const bf16x8*)(qb + ((size_t)(b * NTOK + tok)) * 64 + ks * 32 + q4 * 8);
                qf[si][ks] = v;
            }
        }
    }

    floatx4 accO[3][4];
    #pragma unroll
    for (int si = 0; si < 3; ++si)
        #pragma unroll
        for (int th = 0; th < 4; ++th) accO[si][th] = floatx4{0.f, 0.f, 0.f, 0.f};
    float rs[3][4] = {};

    const bf16_t* kbb = kb + (size_t)b * NTOK * 64;
    const bf16_t* vtb = vt + (size_t)b * 64 * NTOK;

    bool pmask = (m_ == 0) || (m_ == 15);   // halo cols: owned by neighbor wave

    // K B-frag: K[tok=aw0+m_][d=32ks+8q4+j]
    auto load_k = [&](int it, bf16x8* kd) {
        int aw0 = 56 * it - 1 + 14 * w;
        int tok = aw0 + m_;
        bool ok = (tok >= 0) && (tok < NTOK);
        #pragma unroll
        for (int ks = 0; ks < 2; ++ks) {
            bf16x8 v = {};
            if (ok) v = *(const bf16x8*)(kbb + (size_t)tok * 64 + ks * 32 + q4 * 8);
            kd[ks] = v;
        }
    };
    // V B-frag (per h-tile th): V[tok=aw0+8q4+j][h=16th+m_]
    auto load_v = [&](int it, bf16x8* vd) {
        int aw0 = 56 * it - 1 + 14 * w;
        int col = aw0 + 8 * q4;
        #pragma unroll
        for (int th = 0; th < 4; ++th) {
            size_t hrow = (size_t)(16 * th + m_) * NTOK;
            if (col < 0 || col > NTOK - 8) {
                // exact per-element gather on both edges (R5/R7 lesson): vd[j] = V[col+j] or 0
                bf16x8 v = {};
                #pragma unroll
                for (int j = 0; j < 8; ++j) {
                    int tk = col + j;
                    if (tk >= 0 && tk < NTOK) v[j] = vtb[hrow + tk];
                }
                vd[th] = v;
            } else {
                vd[th] = *(const bf16x8*)(vtb + hrow + col);
            }
        }
    };

    bf16x8 kf[2];
    load_k(it0, kf);

    for (int it = it0; it < itEnd; ++it) {
        // V for this iter: issued now, consumed at iter end (conv covers latency)
        bf16x8 vf[4];
        load_v(it, vf);

        // ---- QK^T: 3 si-tiles x K=64, cols = wave's 16 ----
        floatx4 Cq[3];
        #pragma unroll
        for (int si = 0; si < 3; ++si) {
            floatx4 c = floatx4{0.f, 0.f, 0.f, 0.f};
            #pragma unroll
            for (int ks = 0; ks < 2; ++ks)
                c = __builtin_amdgcn_mfma_f32_16x16x32_bf16(qf[si][ks], kf[ks], c, 0, 0, 0);
            Cq[si] = c;
        }

        // prefetch next iter's K
        bf16x8 kn[2] = {};
        bool pf = (it + 1 < itEnd);
        if (pf) load_k(it + 1, kn);

        // ---- conv (rank-3, exact fp32, fully in-wave) + elementwise + P write ----
        #pragma unroll
        for (int si = 0; si < 3; ++si) {
            float a_up = __shfl(Cq[si][3], lane - 16);                       // q4>0
            float b_up = (si > 0) ? __shfl(Cq[si - 1][3], lane + 48) : 0.f;  // q4==0
            float c_dn = __shfl(Cq[si][0], lane + 16);                       // q4<3
            float d_dn = (si < 2) ? __shfl(Cq[si + 1][0], lane - 48) : 0.f;  // q4==3
            float up[4], dn[4];
            up[0] = (q4 > 0) ? a_up : b_up;   // si==0,q4==0 -> 0 (row f=0 is discarded halo)
            up[1] = Cq[si][0]; up[2] = Cq[si][1]; up[3] = Cq[si][2];
            dn[0] = Cq[si][1]; dn[1] = Cq[si][2]; dn[2] = Cq[si][3];
            dn[3] = (q4 < 3) ? c_dn : d_dn;   // si==2,q4==3 -> 0 (row f=47 discarded)

            float G0[4], G1[4], G2[4];
            #pragma unroll
            for (int r = 0; r < 4; ++r) {
                float cu = Cq[si][r];
                G0[r] = cw[0] * up[r] + cw[3] * cu + cw[6] * dn[r];
                G1[r] = cw[1] * up[r] + cw[4] * cu + cw[7] * dn[r];
                G2[r] = cw[2] * up[r] + cw[5] * cu + cw[8] * dn[r];
            }
            #pragma unroll
            for (int r = 0; r < 4; ++r) {
                float e0 = __shfl(G0[r], lane - 1);   // valid for m_ in 1..14 (our interior)
                float e2 = __shfl(G2[r], lane + 1);
                float conv = G1[r] + e0 + e2 + cb;
                float sig = __builtin_amdgcn_rcpf(1.f + __expf(-conv));
                float s = fmaxf(Cq[si][r] - sig, 0.f);
                float ev = __expf(s) - 1.f;
                if (pmask) ev = 0.f;              // halo col: neighbor wave owns it
                rs[si][r] += ev;
                pls[(16 * si + 4 * q4 + r) * PST + m_] = (bf16_t)ev;
            }
        }

        // ---- PV (wave-local LDS transpose, NO barrier): partial O over all 64 h ----
        #pragma unroll
        for (int si = 0; si < 3; ++si) {
            bf16x8 af = *(const bf16x8*)(pls + (16 * si + m_) * PST + 8 * q4);  // P[m_][k=8q4+j], k>=16 zero
            #pragma unroll
            for (int th = 0; th < 4; ++th)
                accO[si][th] = __builtin_amdgcn_mfma_f32_16x16x32_bf16(af, vf[th], accO[si][th], 0, 0, 0);
        }

        if (pf) { kf[0] = kn[0]; kf[1] = kn[1]; }
    }

    // ---- epilogue: reduce wave partials in scr, then atomics ----
    __syncthreads();
    #pragma unroll
    for (int ww = 0; ww < 4; ++ww) {
        if (w == ww) {
            #pragma unroll
            for (int si = 0; si < 3; ++si)
                #pragma unroll
                for (int th = 0; th < 4; ++th)
                    #pragma unroll
                    for (int r = 0; r < 4; ++r) {
                        int idx = (16 * si + 4 * q4 + r) * 64 + 16 * th + m_;
                        if (ww == 0) scr[idx] = accO[si][th][r];
                        else         scr[idx] += accO[si][th][r];
                    }
        }
        __syncthreads();
    }
    for (int e = t; e < 2944; e += 256) {      // rows f=1..46, all h
        int f = (e >> 6) + 1, h = e & 63;
        int grow = 46 * bx + f - 1;
        if (grow < NTOK)
            atomicAdd(outp + ((size_t)(b * NTOK + grow)) * 64 + h, scr[f * 64 + h]);
    }
    __syncthreads();
    // rowsum: per-lane partials -> scr[row][16w+m_] -> row reduce
    #pragma unroll
    for (int si = 0; si < 3; ++si)
        #pragma unroll
        for (int r = 0; r < 4; ++r)
            scr[(16 * si + 4 * q4 + r) * 64 + 16 * w + m_] = rs[si][r];
    __syncthreads();
    if (t < 46) {
        int grow = 46 * bx + t;
        if (grow < NTOK) {
            const float4* p4 = (const float4*)(scr + (t + 1) * 64);
            float s = 0.f;
            #pragma unroll
            for (int j = 0; j < 16; ++j) { float4 v = p4[j]; s += v.x + v.y + v.z + v.w; }
            atomicAdd(&rsg[b * NTOK + grow], s);
        }
    }
}

// ---------------- Kernel 3: normalize out /= (rowsum + eps), in place ----------------
__global__ __launch_bounds__(256) void k_norm(float* __restrict__ out,
                                              const float* __restrict__ rsg) {
    int gid = blockIdx.x * 256 + threadIdx.x;   // 524288 float4s
    float4 o = ((float4*)out)[gid];
    float d = rsg[gid >> 4] + 1e-5f;
    float inv = 1.f / d;
    o.x *= inv; o.y *= inv; o.z *= inv; o.w *= inv;
    ((float4*)out)[gid] = o;
}

extern "C" void kernel_launch(void* const* d_in, const int* in_sizes, int n_in,
                              void* d_out, int out_size, void* d_ws, size_t ws_size,
                              hipStream_t stream) {
    const float* x  = (const float*)d_in[0];
    const float* Wq = (const float*)d_in[1];
    const float* bq = (const float*)d_in[2];
    const float* Wk = (const float*)d_in[3];
    const float* bk = (const float*)d_in[4];
    const float* Wv = (const float*)d_in[5];
    const float* bv = (const float*)d_in[6];
    const float* cw = (const float*)d_in[7];
    const float* cb = (const float*)d_in[8];
    float* out = (float*)d_out;

    char* ws = (char*)d_ws;
    bf16_t* wt = (bf16_t*)ws;                               // 96 KB
    bf16_t* qb = (bf16_t*)(ws + 98304);                     // 4 MB
    bf16_t* kb = (bf16_t*)(ws + 98304 + 4194304);           // 4 MB
    bf16_t* vt = (bf16_t*)(ws + 98304 + 8388608);           // 4 MB
    float*  rsg = (float*)(ws + 98304 + 12582912);          // 128 KB

    k_prep<<<dim3(1024), dim3(256), 0, stream>>>(Wq, Wk, Wv, wt, out, rsg);
    k_qkv<<<dim3(1024), dim3(256), 0, stream>>>(x, wt, bq, bk, bv, qb, kb, vt);
    k_attn<<<dim3(GX, 3, BQ), dim3(256), 0, stream>>>(qb, kb, vt, cw, cb, out, rsg);
    k_norm<<<dim3(2048), dim3(256), 0, stream>>>(out, rsg);
}